// Round 5
// baseline (240.867 us; speedup 1.0000x reference)
//
#include <hip/hip_runtime.h>
#include <math.h>

#define B_ 16
#define C_ 67
#define H_ 128
#define W_ 128
#define MAIN_ 64
#define G_ 8
#define K2_ 9
#define PM_ 72
#define PR_ 9

// ---------------- Kernel 1: global average pool ----------------
// grid: B*C blocks, 256 threads. Each block reduces one (b,c) plane (16384 floats).
__global__ __launch_bounds__(256) void pool_kernel(const float* __restrict__ x,
                                                   float* __restrict__ pooled) {
    int bc = blockIdx.x;
    const float4* p4 = (const float4*)(x + (size_t)bc * (H_ * W_));
    int tid = threadIdx.x;
    float s = 0.f;
    const int n4 = H_ * W_ / 4;  // 4096
    for (int i = tid; i < n4; i += 256) {
        float4 v = p4[i];
        s += (v.x + v.y) + (v.z + v.w);
    }
    for (int off = 32; off > 0; off >>= 1) s += __shfl_down(s, off, 64);
    __shared__ float red[4];
    if ((tid & 63) == 0) red[tid >> 6] = s;
    __syncthreads();
    if (tid == 0) {
        float t = (red[0] + red[1]) + (red[2] + red[3]);
        pooled[bc] = t * (1.0f / (H_ * W_));
    }
}

// ---------------- Kernel 2: fused gen + dynamic 3x3 conv (reflect pad) + residual ----------------
// grid: (C_, B_) blocks x 256 threads. Each block:
//   (a) recomputes the dynamic-kernel MLP for its (b, group) into LDS (~0.5us, L2-resident weights)
//   (b) convolves its whole (b,c) plane, 4 px/thread x 16 iters.
__global__ __launch_bounds__(256) void conv_gen_kernel(
    const float* __restrict__ x, const float* __restrict__ pooled,
    const float* __restrict__ w_main, const float* __restrict__ w_gate_main,
    const float* __restrict__ w_rem,  const float* __restrict__ w_gate_rem,
    const float* __restrict__ gm, const float* __restrict__ bm,
    const float* __restrict__ mm, const float* __restrict__ vm,
    const float* __restrict__ gr, const float* __restrict__ br,
    const float* __restrict__ mr, const float* __restrict__ vr,
    float* __restrict__ out)
{
    const int c = blockIdx.x;   // 0..66
    const int b = blockIdx.y;   // 0..15
    const int t = threadIdx.x;

    __shared__ float pl[C_];
    __shared__ float v0s[PM_];   // km0 (main) or kr0 (rem)
    __shared__ float kb9[K2_];   // post-gate/BN values for this block's 9 entries
    __shared__ float wgt[K2_];   // softmaxed weights

    if (t < C_) pl[t] = pooled[b * C_ + t];
    __syncthreads();

    if (c < MAIN_) {
        const int g = c >> 3;
        if (t < PM_) {
            float s = 0.f;
            for (int i = 0; i < C_; ++i) s += pl[i] * w_main[t * C_ + i];
            v0s[t] = s;
        }
        __syncthreads();
        if (t < K2_) {
            int row = g * K2_ + t;
            float gsum = 0.f;
            for (int q = 0; q < PM_; ++q) gsum += v0s[q] * w_gate_main[row * PM_ + q];
            float v = v0s[row] * (1.f / (1.f + expf(-gsum)));
            v = gm[row] * (v - mm[row]) * rsqrtf(vm[row] + 1e-5f) + bm[row];
            kb9[t] = v;
        }
        __syncthreads();
        if (t < K2_) {
            float mx = -1e30f;
            for (int k = 0; k < K2_; ++k) mx = fmaxf(mx, kb9[k]);
            float den = 0.f;
            for (int k = 0; k < K2_; ++k) den += expf(kb9[k] - mx);
            wgt[t] = expf(kb9[t] - mx) / den;
        }
    } else {
        if (t < PR_) {
            float s = 0.f;
            for (int i = 0; i < C_; ++i) s += pl[i] * w_rem[t * C_ + i];
            v0s[t] = s;
        }
        __syncthreads();
        if (t < PR_) {
            float gsum = 0.f;
            for (int q = 0; q < PR_; ++q) gsum += v0s[q] * w_gate_rem[t * PR_ + q];
            float v = v0s[t] * (1.f / (1.f + expf(-gsum)));
            v = gr[t] * (v - mr[t]) * rsqrtf(vr[t] + 1e-5f) + br[t];
            kb9[t] = v;
        }
        __syncthreads();
        if (t < PR_) {
            float mx = -1e30f;
            for (int k = 0; k < K2_; ++k) mx = fmaxf(mx, kb9[k]);
            float den = 0.f;
            for (int k = 0; k < K2_; ++k) den += expf(kb9[k] - mx);
            wgt[t] = expf(kb9[t] - mx) / den;
        }
    }
    __syncthreads();

    const float k0 = wgt[0], k1 = wgt[1], k2 = wgt[2],
                k3 = wgt[3], k4 = wgt[4], k5 = wgt[5],
                k6 = wgt[6], k7 = wgt[7], k8 = wgt[8];

    const size_t bc = (size_t)b * C_ + c;
    const float* xb = x + bc * (H_ * W_);
    float* ob = out + bc * (H_ * W_);
    float* oh = ob + (size_t)B_ * C_ * H_ * W_;

    #pragma unroll
    for (int it = 0; it < 16; ++it) {
        int task = it * 256 + t;         // 0..4095
        int h  = task >> 5;              // 0..127
        int c0 = (task & 31) * 4;        // col start

        int hm = (h == 0) ? 1 : h - 1;
        int hp = (h == H_ - 1) ? H_ - 2 : h + 1;
        int cl = (c0 == 0) ? 1 : c0 - 1;           // reflect left
        int cr = (c0 == W_ - 4) ? W_ - 2 : c0 + 4; // reflect right

        const float* r0 = xb + hm * W_;
        const float* r1 = xb + (size_t)h * W_;
        const float* r2 = xb + hp * W_;

        float4 v0 = *(const float4*)(r0 + c0);
        float a0 = r0[cl], f0 = r0[cr];
        float4 v1 = *(const float4*)(r1 + c0);
        float a1 = r1[cl], f1 = r1[cr];
        float4 v2 = *(const float4*)(r2 + c0);
        float a2 = r2[cl], f2 = r2[cr];

        float4 acc;
        acc.x = k0*a0   + k1*v0.x + k2*v0.y
              + k3*a1   + k4*v1.x + k5*v1.y
              + k6*a2   + k7*v2.x + k8*v2.y;
        acc.y = k0*v0.x + k1*v0.y + k2*v0.z
              + k3*v1.x + k4*v1.y + k5*v1.z
              + k6*v2.x + k7*v2.y + k8*v2.z;
        acc.z = k0*v0.y + k1*v0.z + k2*v0.w
              + k3*v1.y + k4*v1.z + k5*v1.w
              + k6*v2.y + k7*v2.z + k8*v2.w;
        acc.w = k0*v0.z + k1*v0.w + k2*f0
              + k3*v1.z + k4*v1.w + k5*f1
              + k6*v2.z + k7*v2.w + k8*f2;

        size_t off = (size_t)h * W_ + c0;
        *(float4*)(ob + off) = acc;
        float4 hi;
        hi.x = v1.x - acc.x;
        hi.y = v1.y - acc.y;
        hi.z = v1.z - acc.z;
        hi.w = v1.w - acc.w;
        *(float4*)(oh + off) = hi;
    }
}

extern "C" void kernel_launch(void* const* d_in, const int* in_sizes, int n_in,
                              void* d_out, int out_size, void* d_ws, size_t ws_size,
                              hipStream_t stream) {
    const float* x           = (const float*)d_in[0];
    const float* w_main      = (const float*)d_in[1];
    const float* w_gate_main = (const float*)d_in[2];
    const float* w_rem       = (const float*)d_in[3];
    const float* w_gate_rem  = (const float*)d_in[4];
    const float* gm = (const float*)d_in[5];
    const float* bm = (const float*)d_in[6];
    const float* mm = (const float*)d_in[7];
    const float* vm = (const float*)d_in[8];
    const float* gr = (const float*)d_in[9];
    const float* br = (const float*)d_in[10];
    const float* mr = (const float*)d_in[11];
    const float* vr = (const float*)d_in[12];

    float* out = (float*)d_out;
    float* pooled = (float*)d_ws;   // B_*C_ floats

    pool_kernel<<<B_ * C_, 256, 0, stream>>>(x, pooled);

    dim3 grid(C_, B_);
    conv_gen_kernel<<<grid, 256, 0, stream>>>(x, pooled,
                                              w_main, w_gate_main, w_rem, w_gate_rem,
                                              gm, bm, mm, vm, gr, br, mr, vr, out);
}